// Round 1
// baseline (514.470 us; speedup 1.0000x reference)
//
#include <hip/hip_runtime.h>
#include <stdint.h>

typedef __bf16 bf16_t;
typedef __attribute__((ext_vector_type(8))) __bf16 bf16x8;
typedef __attribute__((ext_vector_type(4))) float f32x4;
typedef __attribute__((ext_vector_type(8))) unsigned short ushort8;
typedef __attribute__((ext_vector_type(4))) int int4v;
typedef __attribute__((ext_vector_type(4))) float float4v;

typedef const void __attribute__((address_space(1)))* gptr_t;
typedef void __attribute__((address_space(3)))* lptr_t;

__constant__ float NF4_CB[16] = {
    -1.0f, -0.6961928009986877f, -0.5250730514526367f, -0.39491748809814453f,
    -0.28444138169288635f, -0.18477343022823334f, -0.09105003625154495f, 0.0f,
    0.07958029955625534f, 0.16093020141124725f, 0.24611230194568634f,
    0.33791524171829224f, 0.44070982933044434f, 0.5626170039176941f,
    0.6848514676094055f, 1.0f};

__device__ __forceinline__ unsigned short f32_to_bf16_rne(float f) {
    unsigned int u = __float_as_uint(f);
    u += 0x7FFFu + ((u >> 16) & 1u);
    return (unsigned short)(u >> 16);
}

// Fused preprocessing. LDS codebook, 16 elements/thread.
// Block ranges: [0,wb)->W, [wb,wb+xb)->X, rest->bias.
__global__ void prep_kernel(const int* __restrict__ w_codes,
                            const float* __restrict__ w_absmax,
                            const float* __restrict__ x,
                            const int* __restrict__ b_codes,
                            const float* __restrict__ b_absmax,
                            unsigned short* __restrict__ outW,
                            unsigned short* __restrict__ outA,
                            float* __restrict__ outBias,
                            long w16, long x16, int nbias, long wb, long xb) {
    __shared__ float cb[16];
    if (threadIdx.x < 16) cb[threadIdx.x] = NF4_CB[threadIdx.x];
    __syncthreads();

    long blk = blockIdx.x;
    if (blk < wb) {
        long t = blk * blockDim.x + threadIdx.x;
        if (t >= w16) return;
        long base = t * 16;
        float am = w_absmax[t >> 2];        // 16 codes share one 64-block absmax
        int4v c0 = *(const int4v*)(w_codes + base);
        int4v c1 = *(const int4v*)(w_codes + base + 4);
        int4v c2 = *(const int4v*)(w_codes + base + 8);
        int4v c3 = *(const int4v*)(w_codes + base + 12);
        ushort8 v0, v1;
        v0[0] = f32_to_bf16_rne(cb[c0[0]] * am);
        v0[1] = f32_to_bf16_rne(cb[c0[1]] * am);
        v0[2] = f32_to_bf16_rne(cb[c0[2]] * am);
        v0[3] = f32_to_bf16_rne(cb[c0[3]] * am);
        v0[4] = f32_to_bf16_rne(cb[c1[0]] * am);
        v0[5] = f32_to_bf16_rne(cb[c1[1]] * am);
        v0[6] = f32_to_bf16_rne(cb[c1[2]] * am);
        v0[7] = f32_to_bf16_rne(cb[c1[3]] * am);
        v1[0] = f32_to_bf16_rne(cb[c2[0]] * am);
        v1[1] = f32_to_bf16_rne(cb[c2[1]] * am);
        v1[2] = f32_to_bf16_rne(cb[c2[2]] * am);
        v1[3] = f32_to_bf16_rne(cb[c2[3]] * am);
        v1[4] = f32_to_bf16_rne(cb[c3[0]] * am);
        v1[5] = f32_to_bf16_rne(cb[c3[1]] * am);
        v1[6] = f32_to_bf16_rne(cb[c3[2]] * am);
        v1[7] = f32_to_bf16_rne(cb[c3[3]] * am);
        *(ushort8*)(outW + base) = v0;
        *(ushort8*)(outW + base + 8) = v1;
    } else if (blk < wb + xb) {
        long t = (blk - wb) * blockDim.x + threadIdx.x;
        if (t >= x16) return;
        long base = t * 16;
        float4v f0 = *(const float4v*)(x + base);
        float4v f1 = *(const float4v*)(x + base + 4);
        float4v f2 = *(const float4v*)(x + base + 8);
        float4v f3 = *(const float4v*)(x + base + 12);
        ushort8 v0, v1;
        v0[0] = f32_to_bf16_rne(f0[0]);
        v0[1] = f32_to_bf16_rne(f0[1]);
        v0[2] = f32_to_bf16_rne(f0[2]);
        v0[3] = f32_to_bf16_rne(f0[3]);
        v0[4] = f32_to_bf16_rne(f1[0]);
        v0[5] = f32_to_bf16_rne(f1[1]);
        v0[6] = f32_to_bf16_rne(f1[2]);
        v0[7] = f32_to_bf16_rne(f1[3]);
        v1[0] = f32_to_bf16_rne(f2[0]);
        v1[1] = f32_to_bf16_rne(f2[1]);
        v1[2] = f32_to_bf16_rne(f2[2]);
        v1[3] = f32_to_bf16_rne(f2[3]);
        v1[4] = f32_to_bf16_rne(f3[0]);
        v1[5] = f32_to_bf16_rne(f3[1]);
        v1[6] = f32_to_bf16_rne(f3[2]);
        v1[7] = f32_to_bf16_rne(f3[3]);
        *(ushort8*)(outA + base) = v0;
        *(ushort8*)(outA + base + 8) = v1;
    } else {
        int o = (int)(blk - wb - xb) * blockDim.x + threadIdx.x;
        if (o >= nbias) return;
        outBias[o] = cb[b_codes[o]] * b_absmax[o >> 6];
    }
}

// ---------------------------------------------------------------------------
// NEW main path: 256x256 tile, BK=64, 512 threads (8 waves as 2M x 4N, each
// wave owns a 128x64 output), 16x16x32 MFMA, XOR-swizzled LDS (same scheme as
// the session-verified 256x128 kernel, bank conflicts measured 0), double-
// buffered 128 KiB LDS with COUNTED vmcnt(8): tile t+2's global_load_lds are
// issued right after the barrier that ends compute of tile t, and we only
// ever wait vmcnt(8) (one tile in flight) — the main loop never drains to 0.
// Raw s_barrier (no vmem drain, unlike __syncthreads). Per-wave vmcnt +
// barrier is a valid cross-wave guarantee because all waves run the identical
// symmetric schedule (stage 8 loads/tile each).
// LDS per buffer: A region [0,16384) elems (256 rows x 64), B [16384,32768).
// Row r, 16B k-chunk j stored at region + r*64*2B + ((j ^ (r&7))*16)B.
// Staging: 64 chunks of 1KB per buffer (A: 0..31, B: 32..63); wave w owns
// chunks w*8..w*8+7.
// ---------------------------------------------------------------------------
__global__ __launch_bounds__(512, 2) void gemm_bias_kernel_256x256(
        const bf16_t* __restrict__ A, const bf16_t* __restrict__ B,
        const float* __restrict__ bias, float* __restrict__ C,
        int M, int N, int K) {
    __shared__ __align__(16) bf16_t sAB[65536];   // 128 KiB, 2 x (A 32KB + B 32KB)

    const int t = threadIdx.x;
    const int lane = t & 63;
    const int wave = t >> 6;                      // 0..7

    // Bijective XCD-aware swizzle (valid since nwg % 8 == 0 here; identity
    // otherwise). Gives each XCD a contiguous chunk of tiles -> L2 reuse.
    const int nbx = gridDim.x;
    const int nwg = nbx * (int)gridDim.y;
    int flat = (int)blockIdx.y * nbx + (int)blockIdx.x;
    if ((nwg & 7) == 0) flat = (flat & 7) * (nwg >> 3) + (flat >> 3);
    const int tileM = (flat / nbx) * 256;
    const int tileN = (flat % nbx) * 256;

    // ---- staging addresses (8 x 1KB chunks per wave per tile) ----
    const int rloc = lane >> 3;                   // row within 8-row chunk
    const int jsw  = (lane & 7) ^ rloc;           // swizzled 16B slot
    const bf16_t* srcp[8];
#pragma unroll
    for (int j = 0; j < 8; ++j) {
        int c = wave * 8 + j;                     // 0..63
        int isB = c >> 5;
        int r = (c & 31) * 8 + rloc;              // row within 256-row region
        const bf16_t* base = isB ? (B + (size_t)(tileN + r) * K)
                                 : (A + (size_t)(tileM + r) * K);
        srcp[j] = base + jsw * 8;
    }
    bf16_t* dst0 = &sAB[wave * 4096 + lane * 8];  // chunk stride 512 elems

    auto stage = [&](int bufsel) {
        bf16_t* d = dst0 + bufsel * 32768;
#pragma unroll
        for (int j = 0; j < 8; ++j) {
            __builtin_amdgcn_global_load_lds((gptr_t)srcp[j],
                                             (lptr_t)(d + j * 512), 16, 0, 0);
            srcp[j] += 64;
        }
    };

    // ---- fragment-read addresses (identical formulas to verified kernel) ----
    const int wm = wave >> 2;                     // 0..1  (M half)
    const int wn = wave & 3;                      // 0..3  (N quarter)
    const int la = lane & 15;
    const int jA = lane >> 4;
    const int jj0 = (jA ^ (lane & 7)) * 8;
    const int aoff = (wm * 128 + la) * 64 + jj0;
    const int boff = 16384 + (wn * 64 + la) * 64 + jj0;

    f32x4 acc[8][4] = {};
    const int nt = K >> 6;

    // Prologue: fill both buffers' pipelines; wait only for tile 0.
    stage(0);
    stage(1);
    asm volatile("s_waitcnt vmcnt(8)" ::: "memory");
    __builtin_amdgcn_s_barrier();
    asm volatile("" ::: "memory");

    for (int kt = 0; kt < nt; ++kt) {
        const int base = (kt & 1) << 15;          // buffer select (elems)
#pragma unroll
        for (int kh = 0; kh < 2; ++kh) {
            const int kx = kh << 5;
            bf16x8 a[4], b[4];
#pragma unroll
            for (int i = 0; i < 4; ++i)
                b[i] = *(const bf16x8*)&sAB[((boff + i * 1024) ^ kx) + base];
#pragma unroll
            for (int i = 0; i < 4; ++i)
                a[i] = *(const bf16x8*)&sAB[((aoff + i * 1024) ^ kx) + base];
            __builtin_amdgcn_s_setprio(1);
#pragma unroll
            for (int mi = 0; mi < 4; ++mi)
#pragma unroll
                for (int ni = 0; ni < 4; ++ni)
                    acc[mi][ni] = __builtin_amdgcn_mfma_f32_16x16x32_bf16(
                        a[mi], b[ni], acc[mi][ni], 0, 0, 0);
            __builtin_amdgcn_s_setprio(0);
#pragma unroll
            for (int i = 0; i < 4; ++i)
                a[i] = *(const bf16x8*)&sAB[((aoff + (i + 4) * 1024) ^ kx) + base];
            __builtin_amdgcn_s_setprio(1);
#pragma unroll
            for (int mi = 0; mi < 4; ++mi)
#pragma unroll
                for (int ni = 0; ni < 4; ++ni)
                    acc[mi + 4][ni] = __builtin_amdgcn_mfma_f32_16x16x32_bf16(
                        a[mi], b[ni], acc[mi + 4][ni], 0, 0, 0);
            __builtin_amdgcn_s_setprio(0);
        }
        // Barrier 1: all waves done READING buf[kt&1] -> safe to overwrite.
        asm volatile("" ::: "memory");
        __builtin_amdgcn_s_barrier();
        if (kt + 2 < nt) {
            stage(kt & 1);                        // tile kt+2 -> just-freed buf
            asm volatile("s_waitcnt vmcnt(8)" ::: "memory");  // tile kt+1 landed
        } else {
            asm volatile("s_waitcnt vmcnt(0)" ::: "memory");  // tail drain
        }
        // Barrier 2: all waves have their tile kt+1 loads landed.
        __builtin_amdgcn_s_barrier();
        asm volatile("" ::: "memory");
    }

    const int col0 = tileN + wn * 64 + la;
    const int row0 = tileM + wm * 128 + jA * 4;
    float bv[4];
#pragma unroll
    for (int ni = 0; ni < 4; ++ni) bv[ni] = bias[col0 + ni * 16];
#pragma unroll
    for (int mi = 0; mi < 8; ++mi)
#pragma unroll
        for (int ni = 0; ni < 4; ++ni)
#pragma unroll
            for (int r = 0; r < 4; ++r)
                C[(size_t)(row0 + mi * 16 + r) * N + (col0 + ni * 16)] =
                    acc[mi][ni][r] + bv[ni];
}

// Fallback: 256x128 tile, 512 threads (session-verified, single-buffered).
__global__ __launch_bounds__(512) void gemm_bias_kernel_256(
        const bf16_t* __restrict__ A, const bf16_t* __restrict__ B,
        const float* __restrict__ bias, float* __restrict__ C,
        int M, int N, int K) {
    __shared__ __align__(16) bf16_t sAB[24576];   // 48 KB

    const int t = threadIdx.x;
    const int lane = t & 63;
    const int wave = t >> 6;                      // 0..7
    const int tileM = blockIdx.y * 256;
    const int tileN = blockIdx.x * 128;

    const int rloc = lane >> 3;
    const int jsw  = (lane & 7) ^ rloc;
    const bf16_t* srcp[6];
    bf16_t* dstp[6];
#pragma unroll
    for (int j = 0; j < 6; ++j) {
        int c = wave * 6 + j;
        int isB = (c >= 32);
        int r = (isB ? (c - 32) : c) * 8 + rloc;
        const bf16_t* base = isB ? (B + (size_t)(tileN + r) * K)
                                 : (A + (size_t)(tileM + r) * K);
        srcp[j] = base + jsw * 8;
        dstp[j] = &sAB[c * 512 + lane * 8];
    }

    const int wm = wave >> 1;
    const int wn = wave & 1;
    const int la = lane & 15;
    const int jA = lane >> 4;
    const int jj0 = (jA ^ (lane & 7)) * 8;
    const int aoff = (wm * 64 + la) * 64 + jj0;
    const int boff = 16384 + (wn * 64 + la) * 64 + jj0;

    f32x4 acc[4][4] = {};

    for (int kt = 0; kt < K; kt += 64) {
#pragma unroll
        for (int j = 0; j < 6; ++j) {
            __builtin_amdgcn_global_load_lds((gptr_t)(srcp[j]), (lptr_t)(dstp[j]),
                                             16, 0, 0);
            srcp[j] += 64;
        }
        __syncthreads();

#pragma unroll
        for (int kh = 0; kh < 2; ++kh) {
            const int kx = kh * 32;
            bf16x8 a[4], b[4];
#pragma unroll
            for (int i = 0; i < 4; ++i) a[i] = *(const bf16x8*)&sAB[(aoff + i * 1024) ^ kx];
#pragma unroll
            for (int i = 0; i < 4; ++i) b[i] = *(const bf16x8*)&sAB[(boff + i * 1024) ^ kx];
#pragma unroll
            for (int mi = 0; mi < 4; ++mi)
#pragma unroll
                for (int ni = 0; ni < 4; ++ni)
                    acc[mi][ni] = __builtin_amdgcn_mfma_f32_16x16x32_bf16(
                        a[mi], b[ni], acc[mi][ni], 0, 0, 0);
        }
        __syncthreads();
    }

    const int col0 = tileN + wn * 64 + la;
    const int row0 = tileM + wm * 64 + jA * 4;
    float bv[4];
#pragma unroll
    for (int ni = 0; ni < 4; ++ni) bv[ni] = bias[col0 + ni * 16];
#pragma unroll
    for (int mi = 0; mi < 4; ++mi)
#pragma unroll
        for (int ni = 0; ni < 4; ++ni)
#pragma unroll
            for (int r = 0; r < 4; ++r)
                C[(size_t)(row0 + mi * 16 + r) * N + (col0 + ni * 16)] =
                    acc[mi][ni][r] + bv[ni];
}

// Fallback: 128x128 tile, 256 threads (used only if M % 256 != 0).
__global__ void gemm_bias_kernel_128(const bf16_t* __restrict__ A,
                                     const bf16_t* __restrict__ B,
                                     const float* __restrict__ bias,
                                     float* __restrict__ C,
                                     int M, int N, int K) {
    __shared__ __align__(16) bf16_t sAB[16384];
    const int t = threadIdx.x;
    const int lane = t & 63;
    const int wave = t >> 6;
    const int tileM = blockIdx.y * 128;
    const int tileN = blockIdx.x * 128;

    const int rloc = lane >> 3;
    const int jsw  = (lane & 7) ^ rloc;
    const int chunk0 = wave * 8;
    const int isB = chunk0 >> 4;
    const int ci0 = chunk0 & 15;
    const int r0 = ci0 * 8 + rloc;
    const bf16_t* srcp = (isB ? (B + (size_t)(tileN + r0) * K)
                              : (A + (size_t)(tileM + r0) * K)) + jsw * 8;
    bf16_t* dstp = &sAB[isB * 8192 + ci0 * 512 + lane * 8];
    const size_t srcChunkStride = (size_t)8 * K;

    const int wm = wave >> 1;
    const int wn = wave & 1;
    const int la = lane & 15;
    const int jA = lane >> 4;
    const int jj0 = (jA ^ (lane & 7)) * 8;
    const int aoff = (wm * 64 + la) * 64 + jj0;
    const int boff = 8192 + (wn * 64 + la) * 64 + jj0;

    f32x4 acc[4][4] = {};
    for (int kt = 0; kt < K; kt += 64) {
#pragma unroll
        for (int j8 = 0; j8 < 8; ++j8)
            __builtin_amdgcn_global_load_lds((gptr_t)(srcp + j8 * srcChunkStride),
                                             (lptr_t)(dstp + j8 * 512), 16, 0, 0);
        srcp += 64;
        __syncthreads();
#pragma unroll
        for (int kh = 0; kh < 2; ++kh) {
            const int kx = kh * 32;
            bf16x8 a[4], b[4];
#pragma unroll
            for (int i = 0; i < 4; ++i) a[i] = *(const bf16x8*)&sAB[(aoff + i * 1024) ^ kx];
#pragma unroll
            for (int i = 0; i < 4; ++i) b[i] = *(const bf16x8*)&sAB[(boff + i * 1024) ^ kx];
#pragma unroll
            for (int mi = 0; mi < 4; ++mi)
#pragma unroll
                for (int ni = 0; ni < 4; ++ni)
                    acc[mi][ni] = __builtin_amdgcn_mfma_f32_16x16x32_bf16(
                        a[mi], b[ni], acc[mi][ni], 0, 0, 0);
        }
        __syncthreads();
    }
    const int col0 = tileN + wn * 64 + la;
    const int row0 = tileM + wm * 64 + jA * 4;
    float bv[4];
#pragma unroll
    for (int ni = 0; ni < 4; ++ni) bv[ni] = bias[col0 + ni * 16];
#pragma unroll
    for (int mi = 0; mi < 4; ++mi)
#pragma unroll
        for (int ni = 0; ni < 4; ++ni)
#pragma unroll
            for (int r = 0; r < 4; ++r)
                C[(size_t)(row0 + mi * 16 + r) * N + (col0 + ni * 16)] =
                    acc[mi][ni][r] + bv[ni];
}

extern "C" void kernel_launch(void* const* d_in, const int* in_sizes, int n_in,
                              void* d_out, int out_size, void* d_ws, size_t ws_size,
                              hipStream_t stream) {
    const float* x        = (const float*)d_in[0];
    const int*   w_codes  = (const int*)d_in[1];
    const float* w_absmax = (const float*)d_in[2];
    const int*   b_codes  = (const int*)d_in[3];
    const float* b_absmax = (const float*)d_in[4];
    float* out = (float*)d_out;

    const int  D_OUT = in_sizes[3];
    const long WK    = (long)in_sizes[1];
    const int  D_IN  = (int)(WK / D_OUT);
    const long xN    = (long)in_sizes[0];
    const int  M     = (int)(xN / D_IN);
    const int  N = D_OUT, K = D_IN;

    unsigned short* wsW = (unsigned short*)d_ws;
    unsigned short* wsA = wsW + (size_t)N * K;
    float* wsBias = (float*)(wsA + (size_t)M * K);

    long w16 = WK / 16;
    long x16 = xN / 16;
    long wb = (w16 + 255) / 256;
    long xb = (x16 + 255) / 256;
    long bb = (D_OUT + 255) / 256;
    prep_kernel<<<dim3((unsigned)(wb + xb + bb)), dim3(256), 0, stream>>>(
        w_codes, w_absmax, x, b_codes, b_absmax, wsW, wsA, wsBias,
        w16, x16, D_OUT, wb, xb);

    if (M % 256 == 0 && N % 256 == 0 && K % 64 == 0 && K >= 128) {
        gemm_bias_kernel_256x256<<<dim3(N / 256, M / 256), dim3(512), 0, stream>>>(
            (const bf16_t*)wsA, (const bf16_t*)wsW, wsBias, out, M, N, K);
    } else if (M % 256 == 0) {
        gemm_bias_kernel_256<<<dim3(N / 128, M / 256), dim3(512), 0, stream>>>(
            (const bf16_t*)wsA, (const bf16_t*)wsW, wsBias, out, M, N, K);
    } else {
        gemm_bias_kernel_128<<<dim3(N / 128, M / 128), dim3(256), 0, stream>>>(
            (const bf16_t*)wsA, (const bf16_t*)wsW, wsBias, out, M, N, K);
    }
}